// Round 5
// baseline (289.668 us; speedup 1.0000x reference)
//
#include <hip/hip_runtime.h>
#include <hip/hip_bf16.h>

typedef __bf16 bf16;
typedef __attribute__((ext_vector_type(8))) __bf16 bf16x8;
typedef __attribute__((ext_vector_type(4))) float f32x4;

#define T_SEQ 4096
#define D_EMB 1024
#define HS 64

__device__ __forceinline__ float fexp2(float x) {
#if __has_builtin(__builtin_amdgcn_exp2f)
    return __builtin_amdgcn_exp2f(x);
#else
    return exp2f(x);
#endif
}

// ---------------------------------------------------------------------------
// Kernel 0: cast Wk|Wv (fp32, 64x1024 each) -> bf16 workspace copies.
// ---------------------------------------------------------------------------
__global__ __launch_bounds__(256) void wcast_kernel(
    const float* __restrict__ Wk, const float* __restrict__ Wv,
    bf16* __restrict__ wbf)   // [128][1024]
{
    const int t = blockIdx.x * 256 + threadIdx.x;
    const int base = t * 8;
    const float* src = (base < 65536) ? (Wk + base) : (Wv + base - 65536);
    float4 f0 = *(const float4*)(src);
    float4 f1 = *(const float4*)(src + 4);
    bf16x8 o = {(__bf16)f0.x, (__bf16)f0.y, (__bf16)f0.z, (__bf16)f0.w,
                (__bf16)f1.x, (__bf16)f1.y, (__bf16)f1.z, (__bf16)f1.w};
    *(bf16x8*)(wbf + base) = o;
}

// ---------------------------------------------------------------------------
// Kernel 1: projection GEMM, K-split x4 (unchanged; ~HBM floor on x).
// ---------------------------------------------------------------------------
__global__ __launch_bounds__(256) void proj_kernel(
    const float* __restrict__ x,    // [16384][1024] fp32
    const bf16* __restrict__ wbf,   // [128][1024] bf16
    bf16* __restrict__ kmat,        // [16384][64]
    bf16* __restrict__ qvmat,       // [16384][64]
    bf16* __restrict__ qvT)         // [4][64][4096]
{
    __shared__ float red[4][2048];   // 32 KB

    const int lane = threadIdx.x & 63;
    const int wave = threadIdx.x >> 6;
    const int col  = lane & 15;
    const int quad = lane >> 4;
    const int rowbase = blockIdx.x * 16;

    const float* xrow = x + (size_t)(rowbase + col) * D_EMB + wave * 256;

    f32x4 acc[8];
#pragma unroll
    for (int i = 0; i < 8; ++i) acc[i] = {0.f, 0.f, 0.f, 0.f};

    for (int k0 = 0; k0 < 256; k0 += 32) {
        float4 a0 = *(const float4*)(xrow + k0 + quad * 8);
        float4 a1 = *(const float4*)(xrow + k0 + quad * 8 + 4);
        bf16x8 a = {(__bf16)a0.x, (__bf16)a0.y, (__bf16)a0.z, (__bf16)a0.w,
                    (__bf16)a1.x, (__bf16)a1.y, (__bf16)a1.z, (__bf16)a1.w};
#pragma unroll
        for (int nt = 0; nt < 8; ++nt) {
            const bf16* wrow = wbf + (size_t)(nt * 16 + col) * D_EMB + wave * 256;
            bf16x8 b = *(const bf16x8*)(wrow + k0 + quad * 8);
            acc[nt] = __builtin_amdgcn_mfma_f32_16x16x32_bf16(a, b, acc[nt], 0, 0, 0);
        }
    }

#pragma unroll
    for (int nt = 0; nt < 8; ++nt)
        *(f32x4*)&red[wave][nt * 256 + lane * 4] = acc[nt];
    __syncthreads();

    const int t = threadIdx.x;
    f32x4 s0 = {0.f,0.f,0.f,0.f}, s1 = {0.f,0.f,0.f,0.f};
#pragma unroll
    for (int w = 0; w < 4; ++w) {
        s0 += *(const f32x4*)&red[w][t * 8];
        s1 += *(const f32x4*)&red[w][t * 8 + 4];
    }
    const int nt = t >> 5;
    const int L0 = (t & 31) * 2;
#pragma unroll
    for (int j2 = 0; j2 < 2; ++j2) {
        const int L  = L0 + j2;
        const int q  = L >> 4;
        const int cc = L & 15;
        const int c  = (nt & 3) * 16 + cc;
        f32x4 v = j2 ? s1 : s0;
#pragma unroll
        for (int r = 0; r < 4; ++r) {
            const int grow = rowbase + q * 4 + r;
            bf16 bv = (bf16)v[r];
            if (nt < 4) {
                kmat[(size_t)grow * HS + c] = bv;
            } else {
                qvmat[(size_t)grow * HS + c] = bv;
                const int bb = grow >> 12;
                const int tt = grow & (T_SEQ - 1);
                qvT[((size_t)bb * HS + c) * T_SEQ + tt] = bv;
            }
        }
    }
}

// ---------------------------------------------------------------------------
// Kernel 2: split-K causal attention, fixed-offset softmax, q = v.
// Grid 8192: block = (batch, q-group, 16-tile key chunk); heavy groups first.
// 4 waves split the chunk round-robin; in-block LDS combine; fp32 atomicAdd
// of partial (O, l) into zeroed accumulators (2^-24 offset cancels in O/l).
// ---------------------------------------------------------------------------
__global__ __launch_bounds__(256, 4) void attn_kernel(
    const bf16* __restrict__ kmat,   // [B*T][64]
    const bf16* __restrict__ qvmat,  // [B*T][64]
    const bf16* __restrict__ qvT,    // [B][64][T]
    float* __restrict__ o_acc,       // [B*T][64] fp32 (zeroed)
    float* __restrict__ l_acc)       // [B*T] fp32 (zeroed)
{
    __shared__ bf16 plds[4][16][40];                 // P roundtrip, 5 KB
    __shared__ __align__(16) float obuf[4][16][68];  // O partials, 17.4 KB
    __shared__ float lbuf[4][16];

    const int lane = threadIdx.x & 63;
    const int wave = threadIdx.x >> 6;
    const int col  = lane & 15;
    const int quad = lane >> 4;

    const int idx = blockIdx.x;
    const int c   = idx & 7;             // key chunk 0..7
    const int bg  = idx >> 3;
    const int b   = bg & 3;
    const int g   = 255 - (bg >> 2);     // heavy groups dispatch first
    const int q0  = g * 16;

    const int nk = (q0 + 16 + 31) >> 5;  // causal tile count for this group
    const int tbeg = c * 16;
    if (tbeg >= nk) return;              // block-uniform empty exit
    const int tend = (nk < tbeg + 16) ? nk : tbeg + 16;

    const bf16* qvb = qvmat + (size_t)b * T_SEQ * HS;
    const bf16* kb  = kmat  + (size_t)b * T_SEQ * HS;
    const bf16* vTb = qvT   + (size_t)b * HS * T_SEQ;

    bf16x8 qf0 = *(const bf16x8*)(qvb + (size_t)(q0 + col) * HS + quad * 8);
    bf16x8 qf1 = *(const bf16x8*)(qvb + (size_t)(q0 + col) * HS + 32 + quad * 8);

    f32x4 o[4];
    float lp[4];
#pragma unroll
    for (int h = 0; h < 4; ++h) o[h] = {0.f, 0.f, 0.f, 0.f};
#pragma unroll
    for (int r = 0; r < 4; ++r) lp[r] = 0.f;

    const float sc = 0.125f * 1.44269504088896f;

    bf16x8 kc[4], vc[4];
    int t = tbeg + wave;
    if (t < tend) {
        const int s0 = t * 32;
        const bf16* kr0 = kb + (size_t)(s0 + col) * HS;
        const bf16* kr1 = kb + (size_t)(s0 + 16 + col) * HS;
        kc[0] = *(const bf16x8*)(kr0 + quad * 8);
        kc[1] = *(const bf16x8*)(kr0 + 32 + quad * 8);
        kc[2] = *(const bf16x8*)(kr1 + quad * 8);
        kc[3] = *(const bf16x8*)(kr1 + 32 + quad * 8);
#pragma unroll
        for (int h = 0; h < 4; ++h)
            vc[h] = *(const bf16x8*)(vTb + (size_t)(h * 16 + col) * T_SEQ + s0 + quad * 8);
    }

    while (t < tend) {
        const int tn = t + 4;
        const int tl = (tn < tend) ? tn : t;   // clamp: harmless reload at end
        // ---- prefetch tile tl ----
        bf16x8 kn[4], vn[4];
        {
            const int s0n = tl * 32;
            const bf16* kr0 = kb + (size_t)(s0n + col) * HS;
            const bf16* kr1 = kb + (size_t)(s0n + 16 + col) * HS;
            kn[0] = *(const bf16x8*)(kr0 + quad * 8);
            kn[1] = *(const bf16x8*)(kr0 + 32 + quad * 8);
            kn[2] = *(const bf16x8*)(kr1 + quad * 8);
            kn[3] = *(const bf16x8*)(kr1 + 32 + quad * 8);
#pragma unroll
            for (int h = 0; h < 4; ++h)
                vn[h] = *(const bf16x8*)(vTb + (size_t)(h * 16 + col) * T_SEQ + s0n + quad * 8);
        }

        // ---- compute tile t ----
        const int s0 = t * 32;
        float p[2][4];
#pragma unroll
        for (int ntile = 0; ntile < 2; ++ntile) {
            f32x4 a4 = {0.f, 0.f, 0.f, 0.f};
            a4 = __builtin_amdgcn_mfma_f32_16x16x32_bf16(qf0, kc[ntile * 2], a4, 0, 0, 0);
            a4 = __builtin_amdgcn_mfma_f32_16x16x32_bf16(qf1, kc[ntile * 2 + 1], a4, 0, 0, 0);
#pragma unroll
            for (int r = 0; r < 4; ++r)
                p[ntile][r] = fexp2(fmaf(a4[r], sc, -24.f));
        }

        if (t == nk - 1) {   // causal mask on the diagonal tile
#pragma unroll
            for (int ntile = 0; ntile < 2; ++ntile)
#pragma unroll
                for (int r = 0; r < 4; ++r)
                    if (s0 + ntile * 16 + col > q0 + quad * 4 + r)
                        p[ntile][r] = 0.f;
        }

#pragma unroll
        for (int r = 0; r < 4; ++r) lp[r] += p[0][r] + p[1][r];

        // ---- P: C-layout -> LDS -> A-layout (wave-private, in-order DS) ----
#pragma unroll
        for (int ntile = 0; ntile < 2; ++ntile)
#pragma unroll
            for (int r = 0; r < 4; ++r)
                plds[wave][quad * 4 + r][ntile * 16 + col] = (bf16)p[ntile][r];
        bf16x8 pa = *(const bf16x8*)&plds[wave][col][quad * 8];

        // ---- O += P V ----
#pragma unroll
        for (int h = 0; h < 4; ++h)
            o[h] = __builtin_amdgcn_mfma_f32_16x16x32_bf16(pa, vc[h], o[h], 0, 0, 0);

#pragma unroll
        for (int i = 0; i < 4; ++i) { kc[i] = kn[i]; vc[i] = vn[i]; }
        t = tn;
    }

    // ---- per-wave row-sum of l, write partials ----
#pragma unroll
    for (int r = 0; r < 4; ++r) {
        float lr = lp[r];
#pragma unroll
        for (int off = 1; off < 16; off <<= 1)
            lr += __shfl_xor(lr, off, 64);
        if (col == 0) lbuf[wave][quad * 4 + r] = lr;
    }
#pragma unroll
    for (int h = 0; h < 4; ++h)
#pragma unroll
        for (int r = 0; r < 4; ++r)
            obuf[wave][quad * 4 + r][h * 16 + col] = o[h][r];
    __syncthreads();

    // ---- combine within block, atomicAdd partial into accumulators ----
    const int tid = threadIdx.x;
    const int row = tid >> 4;
    const int c4  = (tid & 15) * 4;
    f32x4 os = {0.f, 0.f, 0.f, 0.f};
    float ls = 0.f;
#pragma unroll
    for (int w = 0; w < 4; ++w) {
        os += *(const f32x4*)&obuf[w][row][c4];
        ls += lbuf[w][row];
    }
    float* dst = o_acc + ((size_t)b * T_SEQ + q0 + row) * HS + c4;
    atomicAdd(dst + 0, os[0]);
    atomicAdd(dst + 1, os[1]);
    atomicAdd(dst + 2, os[2]);
    atomicAdd(dst + 3, os[3]);
    if ((tid & 15) == 0) atomicAdd(l_acc + (size_t)b * T_SEQ + q0 + row, ls);
}

// ---------------------------------------------------------------------------
// Kernel 3: normalize out = O / l.
// ---------------------------------------------------------------------------
__global__ __launch_bounds__(256) void norm_kernel(
    const float* __restrict__ o_acc, const float* __restrict__ l_acc,
    float* __restrict__ out)
{
    const int i = blockIdx.x * 256 + threadIdx.x;   // 0 .. 1048575
    out[i] = o_acc[i] / l_acc[i >> 6];
}

extern "C" void kernel_launch(void* const* d_in, const int* in_sizes, int n_in,
                              void* d_out, int out_size, void* d_ws, size_t ws_size,
                              hipStream_t stream) {
    const float* x  = (const float*)d_in[0];
    const float* Wk = (const float*)d_in[1];
    const float* Wv = (const float*)d_in[2];
    float* out = (float*)d_out;

    bf16* ws    = (bf16*)d_ws;
    bf16* wbf   = ws;                                    // 256 KB
    bf16* kmat  = ws + (size_t)128 * 1024;               // 2 MB
    bf16* qvmat = kmat + (size_t)16384 * 64;             // 2 MB
    bf16* qvT   = qvmat + (size_t)16384 * 64;            // 2 MB
    float* o_acc = (float*)(qvT + (size_t)16384 * 64);   // 4 MB
    float* l_acc = o_acc + (size_t)16384 * 64;           // 64 KB

    hipMemsetAsync(o_acc, 0, ((size_t)16384 * 64 + 16384) * sizeof(float), stream);
    wcast_kernel<<<64, 256, 0, stream>>>(Wk, Wv, wbf);
    proj_kernel<<<1024, 256, 0, stream>>>(x, wbf, kmat, qvmat, qvT);
    attn_kernel<<<8192, 256, 0, stream>>>(kmat, qvmat, qvT, o_acc, l_acc);
    norm_kernel<<<4096, 256, 0, stream>>>(o_acc, l_acc, out);
}

// Round 6
// 202.347 us; speedup vs baseline: 1.4315x; 1.4315x over previous
//
#include <hip/hip_runtime.h>
#include <hip/hip_bf16.h>

typedef __bf16 bf16;
typedef __attribute__((ext_vector_type(8))) __bf16 bf16x8;
typedef __attribute__((ext_vector_type(4))) float f32x4;

#define T_SEQ 4096
#define D_EMB 1024
#define HS 64
#define NW 8          // waves per attention block

__device__ __forceinline__ float fexp2(float x) {
#if __has_builtin(__builtin_amdgcn_exp2f)
    return __builtin_amdgcn_exp2f(x);
#else
    return exp2f(x);
#endif
}

// ---------------------------------------------------------------------------
// Kernel 0: cast Wk|Wv (fp32, 64x1024 each) -> bf16 workspace copies.
// ---------------------------------------------------------------------------
__global__ __launch_bounds__(256) void wcast_kernel(
    const float* __restrict__ Wk, const float* __restrict__ Wv,
    bf16* __restrict__ wbf)   // [128][1024]
{
    const int t = blockIdx.x * 256 + threadIdx.x;
    const int base = t * 8;
    const float* src = (base < 65536) ? (Wk + base) : (Wv + base - 65536);
    float4 f0 = *(const float4*)(src);
    float4 f1 = *(const float4*)(src + 4);
    bf16x8 o = {(__bf16)f0.x, (__bf16)f0.y, (__bf16)f0.z, (__bf16)f0.w,
                (__bf16)f1.x, (__bf16)f1.y, (__bf16)f1.z, (__bf16)f1.w};
    *(bf16x8*)(wbf + base) = o;
}

// ---------------------------------------------------------------------------
// Kernel 1: projection GEMM, K-split x4 (unchanged; ~HBM floor on x).
// ---------------------------------------------------------------------------
__global__ __launch_bounds__(256) void proj_kernel(
    const float* __restrict__ x,    // [16384][1024] fp32
    const bf16* __restrict__ wbf,   // [128][1024] bf16
    bf16* __restrict__ kmat,        // [16384][64]
    bf16* __restrict__ qvmat,       // [16384][64]
    bf16* __restrict__ qvT)         // [4][64][4096]
{
    __shared__ float red[4][2048];   // 32 KB

    const int lane = threadIdx.x & 63;
    const int wave = threadIdx.x >> 6;
    const int col  = lane & 15;
    const int quad = lane >> 4;
    const int rowbase = blockIdx.x * 16;

    const float* xrow = x + (size_t)(rowbase + col) * D_EMB + wave * 256;

    f32x4 acc[8];
#pragma unroll
    for (int i = 0; i < 8; ++i) acc[i] = {0.f, 0.f, 0.f, 0.f};

    for (int k0 = 0; k0 < 256; k0 += 32) {
        float4 a0 = *(const float4*)(xrow + k0 + quad * 8);
        float4 a1 = *(const float4*)(xrow + k0 + quad * 8 + 4);
        bf16x8 a = {(__bf16)a0.x, (__bf16)a0.y, (__bf16)a0.z, (__bf16)a0.w,
                    (__bf16)a1.x, (__bf16)a1.y, (__bf16)a1.z, (__bf16)a1.w};
#pragma unroll
        for (int nt = 0; nt < 8; ++nt) {
            const bf16* wrow = wbf + (size_t)(nt * 16 + col) * D_EMB + wave * 256;
            bf16x8 b = *(const bf16x8*)(wrow + k0 + quad * 8);
            acc[nt] = __builtin_amdgcn_mfma_f32_16x16x32_bf16(a, b, acc[nt], 0, 0, 0);
        }
    }

#pragma unroll
    for (int nt = 0; nt < 8; ++nt)
        *(f32x4*)&red[wave][nt * 256 + lane * 4] = acc[nt];
    __syncthreads();

    const int t = threadIdx.x;
    f32x4 s0 = {0.f,0.f,0.f,0.f}, s1 = {0.f,0.f,0.f,0.f};
#pragma unroll
    for (int w = 0; w < 4; ++w) {
        s0 += *(const f32x4*)&red[w][t * 8];
        s1 += *(const f32x4*)&red[w][t * 8 + 4];
    }
    const int nt = t >> 5;
    const int L0 = (t & 31) * 2;
#pragma unroll
    for (int j2 = 0; j2 < 2; ++j2) {
        const int L  = L0 + j2;
        const int q  = L >> 4;
        const int cc = L & 15;
        const int c  = (nt & 3) * 16 + cc;
        f32x4 v = j2 ? s1 : s0;
#pragma unroll
        for (int r = 0; r < 4; ++r) {
            const int grow = rowbase + q * 4 + r;
            bf16 bv = (bf16)v[r];
            if (nt < 4) {
                kmat[(size_t)grow * HS + c] = bv;
            } else {
                qvmat[(size_t)grow * HS + c] = bv;
                const int bb = grow >> 12;
                const int tt = grow & (T_SEQ - 1);
                qvT[((size_t)bb * HS + c) * T_SEQ + tt] = bv;
            }
        }
    }
}

// ---------------------------------------------------------------------------
// Kernel 2: causal attention, fixed-offset softmax, q = v.
// 512 blocks x 512 threads (8 waves). Block handles q-group pair (g, 255-g)
// of one batch (~130 key-tiles, balanced). 8 waves split a group's tiles
// round-robin; latency hidden by TLP (target 6 waves/SIMD), not register
// prefetch (compiler drops it — rounds 4/5). In-block LDS combine, no atomics.
// ---------------------------------------------------------------------------
__global__ __launch_bounds__(512, 6) void attn_kernel(
    const bf16* __restrict__ kmat,   // [B*T][64]
    const bf16* __restrict__ qvmat,  // [B*T][64]
    const bf16* __restrict__ qvT,    // [B][64][T]
    float* __restrict__ out)         // [B*T][64] fp32
{
    __shared__ bf16 plds[NW][16][40];                 // P roundtrip, 10 KB
    __shared__ __align__(16) float obuf[NW][16][68];  // O partials, 34.8 KB
    __shared__ float lbuf[NW][16];

    const int lane = threadIdx.x & 63;
    const int wave = threadIdx.x >> 6;
    const int col  = lane & 15;
    const int quad = lane >> 4;

    const int b     = blockIdx.x >> 7;     // 0..3
    const int pairg = blockIdx.x & 127;    // 0..127

    const bf16* qvb = qvmat + (size_t)b * T_SEQ * HS;
    const bf16* kb  = kmat  + (size_t)b * T_SEQ * HS;
    const bf16* vTb = qvT   + (size_t)b * HS * T_SEQ;

    const float sc = 0.125f * 1.44269504088896f;

#pragma unroll 1
    for (int half = 0; half < 2; ++half) {
        const int g  = half ? (255 - pairg) : pairg;
        const int q0 = g * 16;

        bf16x8 qf0 = *(const bf16x8*)(qvb + (size_t)(q0 + col) * HS + quad * 8);
        bf16x8 qf1 = *(const bf16x8*)(qvb + (size_t)(q0 + col) * HS + 32 + quad * 8);

        f32x4 o[4];
        float lp[4];
#pragma unroll
        for (int h = 0; h < 4; ++h) o[h] = {0.f, 0.f, 0.f, 0.f};
#pragma unroll
        for (int r = 0; r < 4; ++r) lp[r] = 0.f;

        const int nk = (q0 + 16 + 31) >> 5;   // causal tile count

#pragma unroll 1
        for (int t = wave; t < nk; t += NW) {
            const int s0 = t * 32;

            // ---- tile loads (independent; single vmcnt wait below) ----
            const bf16* kr0 = kb + (size_t)(s0 + col) * HS;
            const bf16* kr1 = kb + (size_t)(s0 + 16 + col) * HS;
            bf16x8 k0 = *(const bf16x8*)(kr0 + quad * 8);
            bf16x8 k1 = *(const bf16x8*)(kr0 + 32 + quad * 8);
            bf16x8 k2 = *(const bf16x8*)(kr1 + quad * 8);
            bf16x8 k3 = *(const bf16x8*)(kr1 + 32 + quad * 8);
            bf16x8 vc[4];
#pragma unroll
            for (int h = 0; h < 4; ++h)
                vc[h] = *(const bf16x8*)(vTb + (size_t)(h * 16 + col) * T_SEQ + s0 + quad * 8);

            // ---- S = Q K^T, p = exp2(S*sc - 24) ----
            float p[2][4];
            {
                f32x4 a4 = {0.f, 0.f, 0.f, 0.f};
                a4 = __builtin_amdgcn_mfma_f32_16x16x32_bf16(qf0, k0, a4, 0, 0, 0);
                a4 = __builtin_amdgcn_mfma_f32_16x16x32_bf16(qf1, k1, a4, 0, 0, 0);
#pragma unroll
                for (int r = 0; r < 4; ++r)
                    p[0][r] = fexp2(fmaf(a4[r], sc, -24.f));
            }
            {
                f32x4 a4 = {0.f, 0.f, 0.f, 0.f};
                a4 = __builtin_amdgcn_mfma_f32_16x16x32_bf16(qf0, k2, a4, 0, 0, 0);
                a4 = __builtin_amdgcn_mfma_f32_16x16x32_bf16(qf1, k3, a4, 0, 0, 0);
#pragma unroll
                for (int r = 0; r < 4; ++r)
                    p[1][r] = fexp2(fmaf(a4[r], sc, -24.f));
            }

            if (t == nk - 1) {   // causal mask: zero masked probabilities
#pragma unroll
                for (int ntile = 0; ntile < 2; ++ntile)
#pragma unroll
                    for (int r = 0; r < 4; ++r)
                        if (s0 + ntile * 16 + col > q0 + quad * 4 + r)
                            p[ntile][r] = 0.f;
            }

#pragma unroll
            for (int r = 0; r < 4; ++r) lp[r] += p[0][r] + p[1][r];

            // ---- P: C-layout -> LDS -> A-layout (wave-private, in-order DS) ----
#pragma unroll
            for (int ntile = 0; ntile < 2; ++ntile)
#pragma unroll
                for (int r = 0; r < 4; ++r)
                    plds[wave][quad * 4 + r][ntile * 16 + col] = (bf16)p[ntile][r];
            bf16x8 pa = *(const bf16x8*)&plds[wave][col][quad * 8];

            // ---- O += P V ----
#pragma unroll
            for (int h = 0; h < 4; ++h)
                o[h] = __builtin_amdgcn_mfma_f32_16x16x32_bf16(pa, vc[h], o[h], 0, 0, 0);
        }

        // ---- per-wave row-sum of l, write partials ----
#pragma unroll
        for (int r = 0; r < 4; ++r) {
            float lr = lp[r];
#pragma unroll
            for (int off = 1; off < 16; off <<= 1)
                lr += __shfl_xor(lr, off, 64);
            if (col == 0) lbuf[wave][quad * 4 + r] = lr;
        }
#pragma unroll
        for (int h = 0; h < 4; ++h)
#pragma unroll
            for (int r = 0; r < 4; ++r)
                obuf[wave][quad * 4 + r][h * 16 + col] = o[h][r];
        __syncthreads();

        // ---- combine: out = (sum_w O_w) / (sum_w l_w) ----
        // 512 threads: each handles (row, 2 cols).
        const int tid = threadIdx.x;
        const int row = tid >> 5;          // 0..15
        const int c2  = (tid & 31) * 2;    // 0,2,..,62
        float2 os = {0.f, 0.f};
        float ls = 0.f;
#pragma unroll
        for (int w = 0; w < NW; ++w) {
            float2 t2 = *(const float2*)&obuf[w][row][c2];
            os.x += t2.x; os.y += t2.y;
            ls += lbuf[w][row];
        }
        float inv = 1.f / ls;
        float* op = out + ((size_t)b * T_SEQ + q0 + row) * HS + c2;
        op[0] = os.x * inv;
        op[1] = os.y * inv;

        __syncthreads();   // obuf/lbuf reused by second group
    }
}

extern "C" void kernel_launch(void* const* d_in, const int* in_sizes, int n_in,
                              void* d_out, int out_size, void* d_ws, size_t ws_size,
                              hipStream_t stream) {
    const float* x  = (const float*)d_in[0];
    const float* Wk = (const float*)d_in[1];
    const float* Wv = (const float*)d_in[2];
    float* out = (float*)d_out;

    bf16* ws    = (bf16*)d_ws;
    bf16* wbf   = ws;                                    // 256 KB
    bf16* kmat  = ws + (size_t)128 * 1024;               // 2 MB
    bf16* qvmat = kmat + (size_t)16384 * 64;             // 2 MB
    bf16* qvT   = qvmat + (size_t)16384 * 64;            // 2 MB

    wcast_kernel<<<64, 256, 0, stream>>>(Wk, Wv, wbf);
    proj_kernel<<<1024, 256, 0, stream>>>(x, wbf, kmat, qvmat, qvT);
    attn_kernel<<<512, 512, 0, stream>>>(kmat, qvmat, qvT, out);
}